// Round 11
// baseline (35.796 us; speedup 1.0000x reference)
//
#include <hip/hip_runtime.h>
#include <hip/hip_bf16.h>
#include <math.h>

#define QN 128
#define SN 128
#define HN 32
#define CN (QN * SN)
#define TILE_R 128   // batch rows per block

typedef unsigned int u32;
using half8   = __attribute__((ext_vector_type(8))) _Float16;
using floatx4 = __attribute__((ext_vector_type(4))) float;

// Direct global->LDS, 16B/lane, no destination VGPRs -> deep MLP.
__device__ __forceinline__ void gload16(const float* g, float* l) {
  __builtin_amdgcn_global_load_lds(
      (const __attribute__((address_space(1))) u32*)(const void*)g,
      (__attribute__((address_space(3))) u32*)(void*)l,
      16, 0, 0);
}

// MFMA grouped-GEMM. Block: 256 threads (4 waves), one q, 128 batch rows;
// wave w owns rows w*32..w*32+31 (two 16-row M-tiles).
// x staged via global_load_lds: each wave issues 16 x 1KB back-to-back
// (16KB in flight/wave -> ~128KB/CU outstanding, Little's-law saturating),
// single 64KB linear LDS buffer. Swizzle rule 21: LDS dest LINEAR
// (uniform base = wid/k literals only -> no scalarization waterfall, the
// R3/R5 failure), global SOURCE chunk pre-XOR'd, read applies same XOR.
// 16B chunk c of row r lives at LDS chunk c^(r&15): A-frag ds_read_b128
// per phase (16 lanes, fixed koct) hits each bank-quad 2x = free (m136).
// B-frags/epilogue identical to passing R9/R10.
__global__ __launch_bounds__(256, 2)
void divenc_kernel(const float* __restrict__ x,
                   const float* __restrict__ W1,
                   const float* __restrict__ b1,
                   const float* __restrict__ W2,
                   const float* __restrict__ b2,
                   float* __restrict__ out) {
  const int q    = blockIdx.x;
  const int b0   = blockIdx.y * TILE_R;
  const int tid  = threadIdx.x;
  const int lane = tid & 63;
  const int wid  = __builtin_amdgcn_readfirstlane(tid >> 6);
  const int nA   = lane & 15;   // n-col / A-row within tile
  const int koct = lane >> 4;   // k-octet 0..3

  __shared__ float xs[TILE_R * SN];  // 64 KB, source-swizzled chunks

  // ---- stage x FIRST (BW-critical stream): wave w stages rows w*32..+31,
  // 16 instrs x 1KB (2 rows each). Dest = uniform base + literal offset.
  {
    const float* tb = x + (size_t)b0 * CN + (size_t)q * SN;
    const int rl = lane >> 5;        // row within pair (0/1)
    const int s  = lane & 31;        // LDS chunk slot this lane fills
    #pragma unroll
    for (int k = 0; k < 16; ++k) {
      const int rloc = wid * 32 + k * 2 + rl;       // local row (per-lane ok)
      const int g    = s ^ (rloc & 15);             // global chunk to fetch
      gload16(tb + (size_t)rloc * CN + g * 4,       // g*16B
              xs + wid * 4096 + k * 256);           // uniform: wid,k only
    }
  }

  // ---- W1 B-frags + epilogue params (overlap with in-flight stage)
  const float* __restrict__ w1q = W1 + (size_t)q * (SN * HN);
  half8 bf[2][4];
  #pragma unroll
  for (int n0 = 0; n0 < 2; ++n0) {
    #pragma unroll
    for (int kk = 0; kk < 4; ++kk) {
      #pragma unroll
      for (int i = 0; i < 8; ++i) {
        const int k = kk * 32 + koct * 8 + i;
        bf[n0][kk][i] = (_Float16)w1q[k * HN + n0 * 16 + nA];
      }
    }
  }
  const float b1a = b1[q * HN + nA],  b1b = b1[q * HN + 16 + nA];
  const float w2a = W2[q * HN + nA],  w2b = W2[q * HN + 16 + nA];
  const float b2q = b2[q];

  __syncthreads();  // vmcnt(0) drain + barrier: all 64KB resident

  // ---- MFMA: A-frag lane holds X[row0+nA][kk*32 + koct*8 + i]
  const floatx4 z = {0.f, 0.f, 0.f, 0.f};
  floatx4 acc[2][2];
  acc[0][0] = z; acc[0][1] = z; acc[1][0] = z; acc[1][1] = z;

  #pragma unroll
  for (int mt = 0; mt < 2; ++mt) {
    const int row = wid * 32 + mt * 16 + nA;
    const float* rowbase = xs + row * SN;
    #pragma unroll
    for (int kk = 0; kk < 4; ++kk) {
      const int g0 = kk * 8 + koct * 2;         // floats kk*32+koct*8 .. +4
      const float4 va = *reinterpret_cast<const float4*>(
          rowbase + ((g0 ^ nA) << 2));
      const float4 vb = *reinterpret_cast<const float4*>(
          rowbase + (((g0 + 1) ^ nA) << 2));    // floats +4 .. +8
      half8 af;
      af[0] = (_Float16)va.x; af[1] = (_Float16)va.y;
      af[2] = (_Float16)va.z; af[3] = (_Float16)va.w;
      af[4] = (_Float16)vb.x; af[5] = (_Float16)vb.y;
      af[6] = (_Float16)vb.z; af[7] = (_Float16)vb.w;
      acc[mt][0] = __builtin_amdgcn_mfma_f32_16x16x32_f16(af, bf[0][kk], acc[mt][0], 0, 0, 0);
      acc[mt][1] = __builtin_amdgcn_mfma_f32_16x16x32_f16(af, bf[1][kk], acc[mt][1], 0, 0, 0);
    }
  }

  // ---- epilogue. C/D: col = nA, row(in tile) = koct*4 + reg.
  #pragma unroll
  for (int mt = 0; mt < 2; ++mt) {
    #pragma unroll
    for (int reg = 0; reg < 4; ++reg) {
      float v0 = acc[mt][0][reg] + b1a;
      v0 = v0 > 0.f ? v0 : expm1f(v0);
      float v1 = acc[mt][1][reg] + b1b;
      v1 = v1 > 0.f ? v1 : expm1f(v1);
      float t = fmaf(v0, w2a, v1 * w2b);
      t += __shfl_xor(t, 1);
      t += __shfl_xor(t, 2);
      t += __shfl_xor(t, 4);
      t += __shfl_xor(t, 8);
      if (nA == 0) {
        const int row = b0 + wid * 32 + mt * 16 + koct * 4 + reg;
        out[(size_t)row * QN + q] = t + b2q;
      }
    }
  }
}

extern "C" void kernel_launch(void* const* d_in, const int* in_sizes, int n_in,
                              void* d_out, int out_size, void* d_ws, size_t ws_size,
                              hipStream_t stream) {
  const float* x  = (const float*)d_in[0];
  const float* W1 = (const float*)d_in[1];
  const float* b1 = (const float*)d_in[2];
  const float* W2 = (const float*)d_in[3];
  const float* b2 = (const float*)d_in[4];
  float* out = (float*)d_out;

  const int B = in_sizes[0] / CN;  // 2048
  dim3 grid(QN, B / TILE_R);
  divenc_kernel<<<grid, 256, 0, stream>>>(x, W1, b1, W2, b2, out);
}

// Round 12
// 32.051 us; speedup vs baseline: 1.1168x; 1.1168x over previous
//
#include <hip/hip_runtime.h>
#include <hip/hip_bf16.h>
#include <math.h>

#define QN 128
#define SN 128
#define HN 32
#define CN (QN * SN)
#define TILE_R 128   // batch rows per block
#define WST 34       // LDS words per k-row of W1 (32 + 2 pad -> 2-way reads)

using half8   = __attribute__((ext_vector_type(8))) _Float16;
using floatx4 = __attribute__((ext_vector_type(4))) float;

// MFMA grouped-GEMM, x direct from global (R9-proven), W1 via LDS.
// Block: 256 threads (4 waves), one q, 128 batch rows; wave w owns rows
// w*32..w*32+31 (two 16-row M-tiles).
// KEY CHANGE vs R9: the W1 B-frag gather (64 scalar global loads/thread =
// 80% of VMEM issue slots for 0.05% of bytes) becomes 4 coalesced dwordx4
// into padded LDS + 64 ds_read_b32 on the DS pipe. Per-thread VMEM: 80->20.
// LDS [k][n] stride-34: frag reads hit each bank exactly 2x = free (m136);
// staging writes are 2x ds_write_b64, 4-way, 16 instrs -> negligible.
__global__ __launch_bounds__(256, 4)
void divenc_kernel(const float* __restrict__ x,
                   const float* __restrict__ W1,
                   const float* __restrict__ b1,
                   const float* __restrict__ W2,
                   const float* __restrict__ b2,
                   float* __restrict__ out) {
  const int q    = blockIdx.x;
  const int b0   = blockIdx.y * TILE_R;
  const int tid  = threadIdx.x;
  const int lane = tid & 63;
  const int wid  = __builtin_amdgcn_readfirstlane(tid >> 6);
  const int nA   = lane & 15;   // n-col / A-row within tile
  const int koct = lane >> 4;   // k-octet 0..3

  __shared__ float w1s[SN * WST];  // 17408 B

  // ---- stage W1[q] (16 KB) coalesced: 4 dwordx4/thread, transposed-pad store
  const float* __restrict__ w1q = W1 + (size_t)q * (SN * HN);
  #pragma unroll
  for (int i = 0; i < 4; ++i) {
    const float4 v = *reinterpret_cast<const float4*>(w1q + i * 1024 + 4 * tid);
    const int k    = i * 32 + (tid >> 3);
    const int ncol = 4 * (tid & 7);
    float* p = &w1s[k * WST + ncol];
    *reinterpret_cast<float2*>(p)     = make_float2(v.x, v.y);
    *reinterpret_cast<float2*>(p + 2) = make_float2(v.z, v.w);
  }
  __syncthreads();

  // ---- B-frags from LDS: lane holds W1[q][kk*32+koct*8+i][n0*16+nA] as fp16
  half8 bf[2][4];
  #pragma unroll
  for (int n0 = 0; n0 < 2; ++n0) {
    #pragma unroll
    for (int kk = 0; kk < 4; ++kk) {
      #pragma unroll
      for (int i = 0; i < 8; ++i) {
        const int k = kk * 32 + koct * 8 + i;
        bf[n0][kk][i] = (_Float16)w1s[k * WST + n0 * 16 + nA];
      }
    }
  }

  const float b1a = b1[q * HN + nA],  b1b = b1[q * HN + 16 + nA];
  const float w2a = W2[q * HN + nA],  w2b = W2[q * HN + 16 + nA];
  const float b2q = b2[q];

  // ---- A-frags direct from global + MFMA (identical to passing R9)
  const floatx4 z = {0.f, 0.f, 0.f, 0.f};
  floatx4 acc[2][2];
  acc[0][0] = z; acc[0][1] = z; acc[1][0] = z; acc[1][1] = z;

  const int row0 = b0 + wid * 32;
  #pragma unroll
  for (int mt = 0; mt < 2; ++mt) {
    const float* __restrict__ rp =
        x + (size_t)(row0 + mt * 16 + nA) * CN + q * SN + koct * 8;
    #pragma unroll
    for (int kk = 0; kk < 4; ++kk) {
      const float4 va = *reinterpret_cast<const float4*>(rp + kk * 32);
      const float4 vb = *reinterpret_cast<const float4*>(rp + kk * 32 + 4);
      half8 af;
      af[0] = (_Float16)va.x; af[1] = (_Float16)va.y;
      af[2] = (_Float16)va.z; af[3] = (_Float16)va.w;
      af[4] = (_Float16)vb.x; af[5] = (_Float16)vb.y;
      af[6] = (_Float16)vb.z; af[7] = (_Float16)vb.w;
      acc[mt][0] = __builtin_amdgcn_mfma_f32_16x16x32_f16(af, bf[0][kk], acc[mt][0], 0, 0, 0);
      acc[mt][1] = __builtin_amdgcn_mfma_f32_16x16x32_f16(af, bf[1][kk], acc[mt][1], 0, 0, 0);
    }
  }

  // ---- epilogue. C/D: col = nA, row(in tile) = koct*4 + reg.
  #pragma unroll
  for (int mt = 0; mt < 2; ++mt) {
    #pragma unroll
    for (int reg = 0; reg < 4; ++reg) {
      float v0 = acc[mt][0][reg] + b1a;
      v0 = v0 > 0.f ? v0 : expm1f(v0);
      float v1 = acc[mt][1][reg] + b1b;
      v1 = v1 > 0.f ? v1 : expm1f(v1);
      float t = fmaf(v0, w2a, v1 * w2b);
      t += __shfl_xor(t, 1);
      t += __shfl_xor(t, 2);
      t += __shfl_xor(t, 4);
      t += __shfl_xor(t, 8);
      if (nA == 0) {
        const int row = row0 + mt * 16 + koct * 4 + reg;
        out[(size_t)row * QN + q] = t + b2q;
      }
    }
  }
}

extern "C" void kernel_launch(void* const* d_in, const int* in_sizes, int n_in,
                              void* d_out, int out_size, void* d_ws, size_t ws_size,
                              hipStream_t stream) {
  const float* x  = (const float*)d_in[0];
  const float* W1 = (const float*)d_in[1];
  const float* b1 = (const float*)d_in[2];
  const float* W2 = (const float*)d_in[3];
  const float* b2 = (const float*)d_in[4];
  float* out = (float*)d_out;

  const int B = in_sizes[0] / CN;  // 2048
  dim3 grid(QN, B / TILE_R);
  divenc_kernel<<<grid, 256, 0, stream>>>(x, W1, b1, W2, b2, out);
}

// Round 13
// 31.770 us; speedup vs baseline: 1.1267x; 1.0088x over previous
//
#include <hip/hip_runtime.h>
#include <hip/hip_bf16.h>
#include <math.h>

#define QN 128
#define SN 128
#define HN 32
#define CN (QN * SN)
#define TILE_R 128   // batch rows per block

using half8   = __attribute__((ext_vector_type(8))) _Float16;
using floatx4 = __attribute__((ext_vector_type(4))) float;

// Grouped-GEMM via MFMA, no LDS, no barriers (R9 body, byte-identical).
// GRID REMAP vs R9: grid=(y,q) instead of (q,y). XCD = bid%8 = blockIdx.x%8,
// so each XCD's resident blocks span ALL q residues mod 8 -> their x-addresses
// (row*65536 + q*512 + off) cover all TCC channel values of addr bits [9:11],
// instead of concentrating each XCD's whole stream onto ~2 of 16 L2 channels
// (the q%8==XCD pathology shared by R8-R12, all pinned at ~4.6 TB/s).
__global__ __launch_bounds__(256, 4)
void divenc_kernel(const float* __restrict__ x,
                   const float* __restrict__ W1,
                   const float* __restrict__ b1,
                   const float* __restrict__ W2,
                   const float* __restrict__ b2,
                   float* __restrict__ out) {
  const int q    = blockIdx.y;
  const int b0   = blockIdx.x * TILE_R;
  const int tid  = threadIdx.x;
  const int lane = tid & 63;
  const int wid  = __builtin_amdgcn_readfirstlane(tid >> 6);
  const int nA   = lane & 15;   // n-col / A-row within tile
  const int koct = lane >> 4;   // k-octet 0..3

  // ---- B-frags: lane holds W1[q][kk*32+koct*8+i][n0*16+nA] as fp16.
  const float* __restrict__ w1q = W1 + (size_t)q * (SN * HN);
  half8 bf[2][4];
  #pragma unroll
  for (int n0 = 0; n0 < 2; ++n0) {
    #pragma unroll
    for (int kk = 0; kk < 4; ++kk) {
      #pragma unroll
      for (int i = 0; i < 8; ++i) {
        const int k = kk * 32 + koct * 8 + i;
        bf[n0][kk][i] = (_Float16)w1q[k * HN + n0 * 16 + nA];
      }
    }
  }

  // ---- A-frags direct from global + MFMA
  floatx4 z = {0.f, 0.f, 0.f, 0.f};
  floatx4 acc[2][2];
  acc[0][0] = z; acc[0][1] = z; acc[1][0] = z; acc[1][1] = z;

  const int row0 = b0 + wid * 32;
  #pragma unroll
  for (int mt = 0; mt < 2; ++mt) {
    const float* __restrict__ rp =
        x + (size_t)(row0 + mt * 16 + nA) * CN + q * SN + koct * 8;
    #pragma unroll
    for (int kk = 0; kk < 4; ++kk) {
      const float4 va = *reinterpret_cast<const float4*>(rp + kk * 32);
      const float4 vb = *reinterpret_cast<const float4*>(rp + kk * 32 + 4);
      half8 af;
      af[0] = (_Float16)va.x; af[1] = (_Float16)va.y;
      af[2] = (_Float16)va.z; af[3] = (_Float16)va.w;
      af[4] = (_Float16)vb.x; af[5] = (_Float16)vb.y;
      af[6] = (_Float16)vb.z; af[7] = (_Float16)vb.w;
      acc[mt][0] = __builtin_amdgcn_mfma_f32_16x16x32_f16(af, bf[0][kk], acc[mt][0], 0, 0, 0);
      acc[mt][1] = __builtin_amdgcn_mfma_f32_16x16x32_f16(af, bf[1][kk], acc[mt][1], 0, 0, 0);
    }
  }

  // ---- epilogue. C/D: col = nA, row (within tile) = koct*4 + reg.
  const float b1a = b1[q * HN + nA],  b1b = b1[q * HN + 16 + nA];
  const float w2a = W2[q * HN + nA],  w2b = W2[q * HN + 16 + nA];
  const float b2q = b2[q];

  #pragma unroll
  for (int mt = 0; mt < 2; ++mt) {
    #pragma unroll
    for (int reg = 0; reg < 4; ++reg) {
      float v0 = acc[mt][0][reg] + b1a;
      v0 = v0 > 0.f ? v0 : expm1f(v0);
      float v1 = acc[mt][1][reg] + b1b;
      v1 = v1 > 0.f ? v1 : expm1f(v1);
      float t = fmaf(v0, w2a, v1 * w2b);
      t += __shfl_xor(t, 1);
      t += __shfl_xor(t, 2);
      t += __shfl_xor(t, 4);
      t += __shfl_xor(t, 8);
      if (nA == 0) {
        const int row = row0 + mt * 16 + koct * 4 + reg;
        out[(size_t)row * QN + q] = t + b2q;
      }
    }
  }
}

extern "C" void kernel_launch(void* const* d_in, const int* in_sizes, int n_in,
                              void* d_out, int out_size, void* d_ws, size_t ws_size,
                              hipStream_t stream) {
  const float* x  = (const float*)d_in[0];
  const float* W1 = (const float*)d_in[1];
  const float* b1 = (const float*)d_in[2];
  const float* W2 = (const float*)d_in[3];
  const float* b2 = (const float*)d_in[4];
  float* out = (float*)d_out;

  const int B = in_sizes[0] / CN;  // 2048
  dim3 grid(B / TILE_R, QN);       // x = row-group, y = q  (decorrelates q from XCD)
  divenc_kernel<<<grid, 256, 0, stream>>>(x, W1, b1, W2, b2, out);
}